// Round 2
// baseline (335.633 us; speedup 1.0000x reference)
//
#include <hip/hip_runtime.h>

#define DD 4096
#define NROWS 16384
#define EPSILON 1e-6f

// Phase 1: y = x + residual; per-row sum(y^2) -> rstd; per-row max|y*gamma|*rstd
// -> global atomicMax (float-as-uint, valid for non-negative floats).
__global__ __launch_bounds__(256) void fused_pass1(
    const float* __restrict__ x, const float* __restrict__ res,
    const float* __restrict__ gamma, float* __restrict__ rstd,
    unsigned int* __restrict__ gmax) {
  const int row = blockIdx.x;
  const int t = threadIdx.x;
  const float4* x4 = (const float4*)(x + (size_t)row * DD);
  const float4* r4 = (const float4*)(res + (size_t)row * DD);
  const float4* g4 = (const float4*)gamma;

  float ss = 0.f, mx = 0.f;
#pragma unroll
  for (int i = 0; i < 4; ++i) {
    const int idx = t + i * 256;  // 1024 float4s per row, coalesced
    float4 xv = x4[idx];
    float4 rv = r4[idx];
    float4 gv = g4[idx];
    float y0 = xv.x + rv.x, y1 = xv.y + rv.y;
    float y2 = xv.z + rv.z, y3 = xv.w + rv.w;
    ss += y0 * y0 + y1 * y1 + y2 * y2 + y3 * y3;
    mx = fmaxf(mx, fmaxf(fmaxf(fabsf(y0 * gv.x), fabsf(y1 * gv.y)),
                         fmaxf(fabsf(y2 * gv.z), fabsf(y3 * gv.w))));
  }

  // wave64 butterfly reduce
#pragma unroll
  for (int off = 32; off > 0; off >>= 1) {
    ss += __shfl_down(ss, off, 64);
    mx = fmaxf(mx, __shfl_down(mx, off, 64));
  }
  __shared__ float s_ss[4], s_mx[4];
  const int wave = t >> 6, lane = t & 63;
  if (lane == 0) { s_ss[wave] = ss; s_mx[wave] = mx; }
  __syncthreads();
  if (t == 0) {
    float tss = s_ss[0] + s_ss[1] + s_ss[2] + s_ss[3];
    float tmx = fmaxf(fmaxf(s_mx[0], s_mx[1]), fmaxf(s_mx[2], s_mx[3]));
    float rs = rsqrtf(tss * (1.0f / DD) + EPSILON);
    rstd[row] = rs;
    // |output| row max; non-negative float compares correctly as uint
    atomicMax(gmax, __float_as_uint(tmx * rs));
  }
}

// Phase 2: recompute y, scale by rstd*gamma*(127/max), round-nearest-even
// (__float2int_rn matches jnp.round), clamp to [-128,127], write as INT32
// (harness reads integer outputs back as np.int32).
__global__ __launch_bounds__(256) void fused_pass2(
    const float* __restrict__ x, const float* __restrict__ res,
    const float* __restrict__ gamma, const float* __restrict__ rstd,
    const unsigned int* __restrict__ gmax, int* __restrict__ out) {
  const int row = blockIdx.x;
  const int t = threadIdx.x;
  const float rs = rstd[row];
  const float inv = 127.0f / __uint_as_float(*gmax);
  const float c = rs * inv;

  const float4* x4 = (const float4*)(x + (size_t)row * DD);
  const float4* r4 = (const float4*)(res + (size_t)row * DD);
  const float4* g4 = (const float4*)gamma;
  int4* o4 = (int4*)(out + (size_t)row * DD);

#pragma unroll
  for (int i = 0; i < 4; ++i) {
    const int idx = t + i * 256;
    float4 xv = x4[idx];
    float4 rv = r4[idx];
    float4 gv = g4[idx];
    int4 q;
    q.x = min(max(__float2int_rn((xv.x + rv.x) * gv.x * c), -128), 127);
    q.y = min(max(__float2int_rn((xv.y + rv.y) * gv.y * c), -128), 127);
    q.z = min(max(__float2int_rn((xv.z + rv.z) * gv.z * c), -128), 127);
    q.w = min(max(__float2int_rn((xv.w + rv.w) * gv.w * c), -128), 127);
    o4[idx] = q;
  }
}

extern "C" void kernel_launch(void* const* d_in, const int* in_sizes, int n_in,
                              void* d_out, int out_size, void* d_ws, size_t ws_size,
                              hipStream_t stream) {
  const float* x     = (const float*)d_in[0];
  const float* res   = (const float*)d_in[1];
  const float* gamma = (const float*)d_in[2];
  int* out = (int*)d_out;

  unsigned int* gmax = (unsigned int*)d_ws;                 // 4 bytes
  float* rstd = (float*)((char*)d_ws + 256);                // 16384 floats

  // gmax must be re-zeroed every call (harness does not re-poison between replays)
  hipMemsetAsync(d_ws, 0, 4, stream);

  fused_pass1<<<NROWS, 256, 0, stream>>>(x, res, gamma, rstd, gmax);
  fused_pass2<<<NROWS, 256, 0, stream>>>(x, res, gamma, rstd, gmax, out);
}

// Round 3
// 205.838 us; speedup vs baseline: 1.6306x; 1.6306x over previous
//
#include <hip/hip_runtime.h>
#include <hip/hip_fp16.h>

#define DD 4096
#define NROWS 16384
#define EPS 1e-6f

// ws layout:
//   +0      : float gmax           (written fresh by reduce_gmax every call)
//   +256    : float rowmax[16384]  (64 KB)
//   +256+64K: float rstd[16384]    (fallback path only)
//   +1MB    : fp16 yq[64M]         (128 MB cache path)

struct H4 { __half2 a, b; };  // 4 halfs, 8 bytes

// ---- Path A: cache normalized output as fp16 ----
__global__ __launch_bounds__(256) void pass1_cache(
    const float* __restrict__ x, const float* __restrict__ res,
    const float* __restrict__ gamma, H4* __restrict__ yq,
    float* __restrict__ rowmax) {
  const int row = blockIdx.x;
  const int t = threadIdx.x;
  const float4* x4 = (const float4*)(x + (size_t)row * DD);
  const float4* r4 = (const float4*)(res + (size_t)row * DD);
  const float4* g4 = (const float4*)gamma;

  float p[16];
  float ss = 0.f, mx = 0.f;
#pragma unroll
  for (int i = 0; i < 4; ++i) {
    const int idx = t + i * 256;  // coalesced
    float4 xv = x4[idx], rv = r4[idx], gv = g4[idx];
    float y0 = xv.x + rv.x, y1 = xv.y + rv.y;
    float y2 = xv.z + rv.z, y3 = xv.w + rv.w;
    ss += y0 * y0 + y1 * y1 + y2 * y2 + y3 * y3;
    float p0 = y0 * gv.x, p1 = y1 * gv.y, p2 = y2 * gv.z, p3 = y3 * gv.w;
    p[4 * i] = p0; p[4 * i + 1] = p1; p[4 * i + 2] = p2; p[4 * i + 3] = p3;
    mx = fmaxf(mx, fmaxf(fmaxf(fabsf(p0), fabsf(p1)),
                         fmaxf(fabsf(p2), fabsf(p3))));
  }
#pragma unroll
  for (int off = 32; off > 0; off >>= 1) {
    ss += __shfl_down(ss, off, 64);
    mx = fmaxf(mx, __shfl_down(mx, off, 64));
  }
  __shared__ float s_ss[4], s_mx[4], s_rs;
  const int wave = t >> 6, lane = t & 63;
  if (lane == 0) { s_ss[wave] = ss; s_mx[wave] = mx; }
  __syncthreads();
  if (t == 0) {
    float tss = s_ss[0] + s_ss[1] + s_ss[2] + s_ss[3];
    float tmx = fmaxf(fmaxf(s_mx[0], s_mx[1]), fmaxf(s_mx[2], s_mx[3]));
    float rs = rsqrtf(tss * (1.0f / DD) + EPS);
    s_rs = rs;
    rowmax[row] = tmx * rs;   // plain store — no atomic
  }
  __syncthreads();
  const float rs = s_rs;
  H4* yrow = yq + (size_t)row * (DD / 4);
#pragma unroll
  for (int i = 0; i < 4; ++i) {
    const int idx = t + i * 256;
    H4 h;
    h.a = __floats2half2_rn(p[4 * i] * rs, p[4 * i + 1] * rs);
    h.b = __floats2half2_rn(p[4 * i + 2] * rs, p[4 * i + 3] * rs);
    yrow[idx] = h;  // 8B coalesced store
  }
}

__global__ __launch_bounds__(1024) void reduce_gmax(
    const float* __restrict__ rowmax, float* __restrict__ gmax) {
  const int t = threadIdx.x;
  float m = 0.f;
#pragma unroll
  for (int i = 0; i < NROWS / 1024; ++i) m = fmaxf(m, rowmax[t + i * 1024]);
#pragma unroll
  for (int off = 32; off > 0; off >>= 1) m = fmaxf(m, __shfl_down(m, off, 64));
  __shared__ float s[16];
  if ((t & 63) == 0) s[t >> 6] = m;
  __syncthreads();
  if (t == 0) {
    float r = s[0];
#pragma unroll
    for (int i = 1; i < 16; ++i) r = fmaxf(r, s[i]);
    *gmax = r;
  }
}

__global__ __launch_bounds__(256) void pass2_cache(
    const __half* __restrict__ yq, const float* __restrict__ gmax,
    int* __restrict__ out) {
  const float c = 127.0f / *gmax;
  const size_t base = ((size_t)blockIdx.x * 256 + threadIdx.x) * 8;
  union { int4 v; __half h[8]; } u;
  u.v = *(const int4*)(yq + base);
  int4 q0, q1;
  q0.x = min(max(__float2int_rn(__half2float(u.h[0]) * c), -128), 127);
  q0.y = min(max(__float2int_rn(__half2float(u.h[1]) * c), -128), 127);
  q0.z = min(max(__float2int_rn(__half2float(u.h[2]) * c), -128), 127);
  q0.w = min(max(__float2int_rn(__half2float(u.h[3]) * c), -128), 127);
  q1.x = min(max(__float2int_rn(__half2float(u.h[4]) * c), -128), 127);
  q1.y = min(max(__float2int_rn(__half2float(u.h[5]) * c), -128), 127);
  q1.z = min(max(__float2int_rn(__half2float(u.h[6]) * c), -128), 127);
  q1.w = min(max(__float2int_rn(__half2float(u.h[7]) * c), -128), 127);
  *(int4*)(out + base) = q0;
  *(int4*)(out + base + 4) = q1;
}

// ---- Path B: fallback (ws too small) — recompute, still atomic-free ----
__global__ __launch_bounds__(256) void pass1_nb(
    const float* __restrict__ x, const float* __restrict__ res,
    const float* __restrict__ gamma, float* __restrict__ rstd,
    float* __restrict__ rowmax) {
  const int row = blockIdx.x;
  const int t = threadIdx.x;
  const float4* x4 = (const float4*)(x + (size_t)row * DD);
  const float4* r4 = (const float4*)(res + (size_t)row * DD);
  const float4* g4 = (const float4*)gamma;
  float ss = 0.f, mx = 0.f;
#pragma unroll
  for (int i = 0; i < 4; ++i) {
    const int idx = t + i * 256;
    float4 xv = x4[idx], rv = r4[idx], gv = g4[idx];
    float y0 = xv.x + rv.x, y1 = xv.y + rv.y;
    float y2 = xv.z + rv.z, y3 = xv.w + rv.w;
    ss += y0 * y0 + y1 * y1 + y2 * y2 + y3 * y3;
    mx = fmaxf(mx, fmaxf(fmaxf(fabsf(y0 * gv.x), fabsf(y1 * gv.y)),
                         fmaxf(fabsf(y2 * gv.z), fabsf(y3 * gv.w))));
  }
#pragma unroll
  for (int off = 32; off > 0; off >>= 1) {
    ss += __shfl_down(ss, off, 64);
    mx = fmaxf(mx, __shfl_down(mx, off, 64));
  }
  __shared__ float s_ss[4], s_mx[4];
  const int wave = t >> 6, lane = t & 63;
  if (lane == 0) { s_ss[wave] = ss; s_mx[wave] = mx; }
  __syncthreads();
  if (t == 0) {
    float tss = s_ss[0] + s_ss[1] + s_ss[2] + s_ss[3];
    float tmx = fmaxf(fmaxf(s_mx[0], s_mx[1]), fmaxf(s_mx[2], s_mx[3]));
    float rs = rsqrtf(tss * (1.0f / DD) + EPS);
    rstd[row] = rs;
    rowmax[row] = tmx * rs;
  }
}

__global__ __launch_bounds__(256) void pass2_nb(
    const float* __restrict__ x, const float* __restrict__ res,
    const float* __restrict__ gamma, const float* __restrict__ rstd,
    const float* __restrict__ gmax, int* __restrict__ out) {
  const int row = blockIdx.x;
  const int t = threadIdx.x;
  const float c = rstd[row] * (127.0f / *gmax);
  const float4* x4 = (const float4*)(x + (size_t)row * DD);
  const float4* r4 = (const float4*)(res + (size_t)row * DD);
  const float4* g4 = (const float4*)gamma;
  int4* o4 = (int4*)(out + (size_t)row * DD);
#pragma unroll
  for (int i = 0; i < 4; ++i) {
    const int idx = t + i * 256;
    float4 xv = x4[idx], rv = r4[idx], gv = g4[idx];
    int4 q;
    q.x = min(max(__float2int_rn((xv.x + rv.x) * gv.x * c), -128), 127);
    q.y = min(max(__float2int_rn((xv.y + rv.y) * gv.y * c), -128), 127);
    q.z = min(max(__float2int_rn((xv.z + rv.z) * gv.z * c), -128), 127);
    q.w = min(max(__float2int_rn((xv.w + rv.w) * gv.w * c), -128), 127);
    o4[idx] = q;
  }
}

extern "C" void kernel_launch(void* const* d_in, const int* in_sizes, int n_in,
                              void* d_out, int out_size, void* d_ws, size_t ws_size,
                              hipStream_t stream) {
  const float* x     = (const float*)d_in[0];
  const float* res   = (const float*)d_in[1];
  const float* gamma = (const float*)d_in[2];
  int* out = (int*)d_out;

  float* gmax   = (float*)d_ws;
  float* rowmax = (float*)((char*)d_ws + 256);
  float* rstd   = (float*)((char*)d_ws + 256 + NROWS * 4);
  const size_t yq_off = (size_t)1 << 20;
  const size_t need = yq_off + (size_t)NROWS * DD * 2;  // ~129 MB

  if (ws_size >= need) {
    H4* yq = (H4*)((char*)d_ws + yq_off);
    pass1_cache<<<NROWS, 256, 0, stream>>>(x, res, gamma, yq, rowmax);
    reduce_gmax<<<1, 1024, 0, stream>>>(rowmax, gmax);
    pass2_cache<<<((size_t)NROWS * DD) / (256 * 8), 256, 0, stream>>>(
        (const __half*)yq, gmax, out);
  } else {
    pass1_nb<<<NROWS, 256, 0, stream>>>(x, res, gamma, rstd, rowmax);
    reduce_gmax<<<1, 1024, 0, stream>>>(rowmax, gmax);
    pass2_nb<<<NROWS, 256, 0, stream>>>(x, res, gamma, rstd, gmax, out);
  }
}

// Round 4
// 203.150 us; speedup vs baseline: 1.6521x; 1.0132x over previous
//
#include <hip/hip_runtime.h>
#include <hip/hip_fp16.h>

#define DD 4096
#define NROWS 16384
#define EPS 1e-6f

// ws layout:
//   +0        : float gmax
//   +256      : float rowmax[16384]
//   +256+64K  : float rstd[16384]
//   +1MB      : fp16 yg[64M] = (x+res)*gamma, UNNORMALIZED (128 MB)

struct H4 { __half2 a, b; };  // 4 halfs, 8 bytes

// Pass 1: streaming. Per iteration: load, compute y=x+res, p=y*gamma,
// accumulate ss/mx, store fp16(p) IMMEDIATELY (no liveness across the
// reduction barrier). Tail reduces only two scalars.
__global__ __launch_bounds__(256) void pass1(
    const float* __restrict__ x, const float* __restrict__ res,
    const float* __restrict__ gamma, H4* __restrict__ yg,
    float* __restrict__ rstd, float* __restrict__ rowmax) {
  const int row = blockIdx.x;
  const int t = threadIdx.x;
  const float4* x4 = (const float4*)(x + (size_t)row * DD);
  const float4* r4 = (const float4*)(res + (size_t)row * DD);
  const float4* g4 = (const float4*)gamma;
  H4* yrow = yg + (size_t)row * (DD / 4);

  float ss = 0.f, mx = 0.f;
#pragma unroll
  for (int i = 0; i < 4; ++i) {
    const int idx = t + i * 256;  // coalesced
    float4 xv = x4[idx], rv = r4[idx], gv = g4[idx];
    float y0 = xv.x + rv.x, y1 = xv.y + rv.y;
    float y2 = xv.z + rv.z, y3 = xv.w + rv.w;
    ss += y0 * y0 + y1 * y1 + y2 * y2 + y3 * y3;
    float p0 = y0 * gv.x, p1 = y1 * gv.y, p2 = y2 * gv.z, p3 = y3 * gv.w;
    mx = fmaxf(mx, fmaxf(fmaxf(fabsf(p0), fabsf(p1)),
                         fmaxf(fabsf(p2), fabsf(p3))));
    H4 h;
    h.a = __floats2half2_rn(p0, p1);
    h.b = __floats2half2_rn(p2, p3);
    yrow[idx] = h;  // store now — nothing stays live across the barrier
  }

#pragma unroll
  for (int off = 32; off > 0; off >>= 1) {
    ss += __shfl_down(ss, off, 64);
    mx = fmaxf(mx, __shfl_down(mx, off, 64));
  }
  __shared__ float s_ss[4], s_mx[4];
  const int wave = t >> 6, lane = t & 63;
  if (lane == 0) { s_ss[wave] = ss; s_mx[wave] = mx; }
  __syncthreads();
  if (t == 0) {
    float tss = s_ss[0] + s_ss[1] + s_ss[2] + s_ss[3];
    float tmx = fmaxf(fmaxf(s_mx[0], s_mx[1]), fmaxf(s_mx[2], s_mx[3]));
    float rs = rsqrtf(tss * (1.0f / DD) + EPS);
    rstd[row] = rs;
    rowmax[row] = tmx * rs;  // |normalized output| row max, f32 exact path
  }
}

__global__ __launch_bounds__(1024) void reduce_gmax(
    const float* __restrict__ rowmax, float* __restrict__ gmax) {
  const int t = threadIdx.x;
  float m = 0.f;
#pragma unroll
  for (int i = 0; i < NROWS / 1024; ++i) m = fmaxf(m, rowmax[t + i * 1024]);
#pragma unroll
  for (int off = 32; off > 0; off >>= 1) m = fmaxf(m, __shfl_down(m, off, 64));
  __shared__ float s[16];
  if ((t & 63) == 0) s[t >> 6] = m;
  __syncthreads();
  if (t == 0) {
    float r = s[0];
#pragma unroll
    for (int i = 1; i < 16; ++i) r = fmaxf(r, s[i]);
    *gmax = r;
  }
}

// Pass 2: q = clamp(rn(fp16(y*gamma) * rstd[row] * 127/gmax)). Each block
// covers 2048 contiguous elements = half a row, so rstd index is uniform.
__global__ __launch_bounds__(256) void pass2(
    const __half* __restrict__ yg, const float* __restrict__ rstd,
    const float* __restrict__ gmax, int* __restrict__ out) {
  const int row = blockIdx.x >> 1;
  const float c = rstd[row] * (127.0f / *gmax);
  const size_t base = ((size_t)blockIdx.x * 256 + threadIdx.x) * 8;
  union { int4 v; __half h[8]; } u;
  u.v = *(const int4*)(yg + base);  // 16B coalesced fp16 load
  int4 q0, q1;
  q0.x = min(max(__float2int_rn(__half2float(u.h[0]) * c), -128), 127);
  q0.y = min(max(__float2int_rn(__half2float(u.h[1]) * c), -128), 127);
  q0.z = min(max(__float2int_rn(__half2float(u.h[2]) * c), -128), 127);
  q0.w = min(max(__float2int_rn(__half2float(u.h[3]) * c), -128), 127);
  q1.x = min(max(__float2int_rn(__half2float(u.h[4]) * c), -128), 127);
  q1.y = min(max(__float2int_rn(__half2float(u.h[5]) * c), -128), 127);
  q1.z = min(max(__float2int_rn(__half2float(u.h[6]) * c), -128), 127);
  q1.w = min(max(__float2int_rn(__half2float(u.h[7]) * c), -128), 127);
  *(int4*)(out + base) = q0;
  *(int4*)(out + base + 4) = q1;
}

// ---- Fallback (ws too small): recompute path, atomic-free ----
__global__ __launch_bounds__(256) void pass1_nb(
    const float* __restrict__ x, const float* __restrict__ res,
    const float* __restrict__ gamma, float* __restrict__ rstd,
    float* __restrict__ rowmax) {
  const int row = blockIdx.x;
  const int t = threadIdx.x;
  const float4* x4 = (const float4*)(x + (size_t)row * DD);
  const float4* r4 = (const float4*)(res + (size_t)row * DD);
  const float4* g4 = (const float4*)gamma;
  float ss = 0.f, mx = 0.f;
#pragma unroll
  for (int i = 0; i < 4; ++i) {
    const int idx = t + i * 256;
    float4 xv = x4[idx], rv = r4[idx], gv = g4[idx];
    float y0 = xv.x + rv.x, y1 = xv.y + rv.y;
    float y2 = xv.z + rv.z, y3 = xv.w + rv.w;
    ss += y0 * y0 + y1 * y1 + y2 * y2 + y3 * y3;
    mx = fmaxf(mx, fmaxf(fmaxf(fabsf(y0 * gv.x), fabsf(y1 * gv.y)),
                         fmaxf(fabsf(y2 * gv.z), fabsf(y3 * gv.w))));
  }
#pragma unroll
  for (int off = 32; off > 0; off >>= 1) {
    ss += __shfl_down(ss, off, 64);
    mx = fmaxf(mx, __shfl_down(mx, off, 64));
  }
  __shared__ float s_ss[4], s_mx[4];
  const int wave = t >> 6, lane = t & 63;
  if (lane == 0) { s_ss[wave] = ss; s_mx[wave] = mx; }
  __syncthreads();
  if (t == 0) {
    float tss = s_ss[0] + s_ss[1] + s_ss[2] + s_ss[3];
    float tmx = fmaxf(fmaxf(s_mx[0], s_mx[1]), fmaxf(s_mx[2], s_mx[3]));
    float rs = rsqrtf(tss * (1.0f / DD) + EPS);
    rstd[row] = rs;
    rowmax[row] = tmx * rs;
  }
}

__global__ __launch_bounds__(256) void pass2_nb(
    const float* __restrict__ x, const float* __restrict__ res,
    const float* __restrict__ gamma, const float* __restrict__ rstd,
    const float* __restrict__ gmax, int* __restrict__ out) {
  const int row = blockIdx.x;
  const int t = threadIdx.x;
  const float c = rstd[row] * (127.0f / *gmax);
  const float4* x4 = (const float4*)(x + (size_t)row * DD);
  const float4* r4 = (const float4*)(res + (size_t)row * DD);
  const float4* g4 = (const float4*)gamma;
  int4* o4 = (int4*)(out + (size_t)row * DD);
#pragma unroll
  for (int i = 0; i < 4; ++i) {
    const int idx = t + i * 256;
    float4 xv = x4[idx], rv = r4[idx], gv = g4[idx];
    int4 q;
    q.x = min(max(__float2int_rn((xv.x + rv.x) * gv.x * c), -128), 127);
    q.y = min(max(__float2int_rn((xv.y + rv.y) * gv.y * c), -128), 127);
    q.z = min(max(__float2int_rn((xv.z + rv.z) * gv.z * c), -128), 127);
    q.w = min(max(__float2int_rn((xv.w + rv.w) * gv.w * c), -128), 127);
    o4[idx] = q;
  }
}

extern "C" void kernel_launch(void* const* d_in, const int* in_sizes, int n_in,
                              void* d_out, int out_size, void* d_ws, size_t ws_size,
                              hipStream_t stream) {
  const float* x     = (const float*)d_in[0];
  const float* res   = (const float*)d_in[1];
  const float* gamma = (const float*)d_in[2];
  int* out = (int*)d_out;

  float* gmax   = (float*)d_ws;
  float* rowmax = (float*)((char*)d_ws + 256);
  float* rstd   = (float*)((char*)d_ws + 256 + NROWS * 4);
  const size_t yg_off = (size_t)1 << 20;
  const size_t need = yg_off + (size_t)NROWS * DD * 2;  // ~129 MB

  if (ws_size >= need) {
    H4* yg = (H4*)((char*)d_ws + yg_off);
    pass1<<<NROWS, 256, 0, stream>>>(x, res, gamma, yg, rstd, rowmax);
    reduce_gmax<<<1, 1024, 0, stream>>>(rowmax, gmax);
    pass2<<<((size_t)NROWS * DD) / 2048, 256, 0, stream>>>(
        (const __half*)yg, rstd, gmax, out);
  } else {
    pass1_nb<<<NROWS, 256, 0, stream>>>(x, res, gamma, rstd, rowmax);
    reduce_gmax<<<1, 1024, 0, stream>>>(rowmax, gmax);
    pass2_nb<<<NROWS, 256, 0, stream>>>(x, res, gamma, rstd, gmax, out);
  }
}